// Round 6
// baseline (407.475 us; speedup 1.0000x reference)
//
#include <hip/hip_runtime.h>

// L2O optimizer fused kernel — R6: R3 per-wave code verbatim, re-geometried to
// 512-thread blocks (8 waves) so the 28KB weight LDS amortizes over more waves:
// 46KB/block -> 3 blocks/CU = 24 waves/CU (was 16). Pure TLP lever; no register
// pipeline (R4/R5 both landed in scratch and regressed).
// Layouts:
//  * B-frag LDS [k/8][n][k%8] (bf16): lane l reads 16B at [l>>4][nt*16+(l&15)].
//  * A and B frags use the SAME k-slot mapping -> correctness independent of HW k-order.
//  * C/D layout (HW-verified): col = lane&15, row = (lane>>4)*4 + reg.

typedef __attribute__((ext_vector_type(8))) short bf16x8;
typedef __attribute__((ext_vector_type(4))) float f32x4;

#define HH 32
#define LL 10
#define NG 128
#define NW 8            // waves per block
#define BLK 512         // threads per block

__device__ __forceinline__ short f2bf(float x) {
  __bf16 b = (__bf16)x;                 // HW v_cvt (pairs fuse to v_cvt_pk_bf16_f32)
  return __builtin_bit_cast(short, b);
}
__device__ __forceinline__ float fsig(float x) {
  return __builtin_amdgcn_rcpf(1.0f + __expf(-x));
}
__device__ __forceinline__ float ftanh(float x) {
  return fmaf(2.0f, __builtin_amdgcn_rcpf(1.0f + __expf(-2.0f * x)), -1.0f);
}

__global__ __launch_bounds__(BLK, 6) void l2o_fused(
    const float* __restrict__ x, const float* __restrict__ grad,
    const float* __restrict__ h0, const float* __restrict__ c0,
    const float* __restrict__ h1, const float* __restrict__ c1,
    const float* __restrict__ W1, const float* __restrict__ b1,
    const float* __restrict__ W2, const float* __restrict__ b2,
    const float* __restrict__ Wih0, const float* __restrict__ Whh0,
    const float* __restrict__ bih0, const float* __restrict__ bhh0,
    const float* __restrict__ Wih1, const float* __restrict__ Whh1,
    const float* __restrict__ bih1, const float* __restrict__ bhh1,
    const float* __restrict__ Wfc, const float* __restrict__ bfc,
    float* __restrict__ out, int BNi)
{
  const size_t BN = (size_t)BNi;
  float* __restrict__ xout  = out;
  float* __restrict__ h0out = out + BN;
  float* __restrict__ c0out = out + BN + BN * HH;
  float* __restrict__ h1out = out + BN + 2 * BN * HH;
  float* __restrict__ c1out = out + BN + 3 * BN * HH;
  float* __restrict__ dout  = out + BN + 4 * BN * HH;

  // Weights in B-fragment chunked layout (bf16): 28KB, shared by 8 waves.
  __shared__ __align__(16) short wih0L[2][NG][8];   // K=10 padded to 16
  __shared__ __align__(16) short whh0L[4][NG][8];
  __shared__ __align__(16) short wih1L[4][NG][8];
  __shared__ __align__(16) short whh1L[4][NG][8];
  __shared__ __align__(16) short tsg0[NW][64][8];   // t dims 0..7 (per wave)
  __shared__ __align__(4)  short tsg1[NW][64][2];   // t dims 8..9
  __shared__ __align__(16) short hsg[NW][4][16][8]; // per-wave, per-st h0n staging

  const int tid = threadIdx.x;
  for (int idx = tid; idx < NG * HH; idx += BLK) {  // 4096
    int n = idx >> 5, k = idx & 31;
    whh0L[k >> 3][n][k & 7] = f2bf(Whh0[n * HH + k]);
    wih1L[k >> 3][n][k & 7] = f2bf(Wih1[n * HH + k]);
    whh1L[k >> 3][n][k & 7] = f2bf(Whh1[n * HH + k]);
  }
  for (int idx = tid; idx < NG * 16; idx += BLK) {  // 2048
    int n = idx >> 4, k = idx & 15;
    wih0L[k >> 3][n][k & 7] = (k < LL) ? f2bf(Wih0[n * LL + k]) : (short)0;
  }

  const int lane = tid & 63;
  const int w = tid >> 6;
  const int col = lane & 15;
  const int g = lane >> 4;
  const int mrow = 4 * g;

  float biasv0[8], biasv1[8];
#pragma unroll
  for (int nt = 0; nt < 8; ++nt) {
    biasv0[nt] = bih0[nt * 16 + col] + bhh0[nt * 16 + col];
    biasv1[nt] = bih1[nt * 16 + col] + bhh1[nt * 16 + col];
  }
  const float wfc0 = Wfc[col], wfc1 = Wfc[16 + col];
  const float bfcv = bfc[0];

  const int ebase = blockIdx.x * (NW * 64) + w * 64;  // this wave's 64 elements
  const bool active = ebase < BNi;                     // wave-uniform tail guard

  if (active) { // ---- t-MLP: one element per lane; weights are uniform scalar loads
    float gv = grad[ebase + lane];
    float sg = (gv > 0.f) ? 1.f : ((gv < 0.f) ? -1.f : 0.f);
    float lg = __logf(fabsf(gv) + 1e-14f);
    float u[LL], t[LL];
#pragma unroll
    for (int j = 0; j < LL; ++j)
      u[j] = ftanh(W1[2 * j] * sg + W1[2 * j + 1] * lg + b1[j]);
#pragma unroll
    for (int j = 0; j < LL; ++j) {
      float a = b2[j];
#pragma unroll
      for (int k = 0; k < LL; ++k) a += W2[j * LL + k] * u[k];
      t[j] = a;
    }
    bf16x8 tv0;
#pragma unroll
    for (int s = 0; s < 8; ++s) tv0[s] = f2bf(t[s]);
    *reinterpret_cast<bf16x8*>(&tsg0[w][lane][0]) = tv0;
    tsg1[w][lane][0] = f2bf(t[8]);
    tsg1[w][lane][1] = f2bf(t[9]);
  }
  __syncthreads();   // weights + t staging visible to all (outside the guard)

  if (active) {
#pragma unroll 1
  for (int st = 0; st < 4; ++st) {
    const int m16 = ebase + st * 16;

    // ---- layer-0 A fragments ----
    bf16x8 a_t = {0, 0, 0, 0, 0, 0, 0, 0};        // K=10 padded; g>=2 all zero
    if (g == 0) a_t = *reinterpret_cast<const bf16x8*>(&tsg0[w][st * 16 + col][0]);
    else if (g == 1) {
      a_t[0] = tsg1[w][st * 16 + col][0];
      a_t[1] = tsg1[w][st * 16 + col][1];
    }
    const float4* hp = reinterpret_cast<const float4*>(h0 + (size_t)(m16 + col) * HH + 8 * g);
    float4 v0 = hp[0], v1 = hp[1];
    bf16x8 a_h0;
    a_h0[0] = f2bf(v0.x); a_h0[1] = f2bf(v0.y); a_h0[2] = f2bf(v0.z); a_h0[3] = f2bf(v0.w);
    a_h0[4] = f2bf(v1.x); a_h0[5] = f2bf(v1.y); a_h0[6] = f2bf(v1.z); a_h0[7] = f2bf(v1.w);

    // c0 loads issued here so HBM latency hides under layer-0 MFMAs
    float c0r[2][4];
#pragma unroll
    for (int kk = 0; kk < 2; ++kk)
#pragma unroll
      for (int r = 0; r < 4; ++r)
        c0r[kk][r] = c0[(size_t)(m16 + mrow + r) * HH + kk * 16 + col];

    f32x4 acc[8];
#pragma unroll
    for (int nt = 0; nt < 8; ++nt) {
      float bv = biasv0[nt];
      f32x4 a = {bv, bv, bv, bv};
      acc[nt] = a;
    }
#pragma unroll
    for (int nt = 0; nt < 8; ++nt) {
      bf16x8 bih = {0, 0, 0, 0, 0, 0, 0, 0};
      if (g < 2) bih = *reinterpret_cast<const bf16x8*>(&wih0L[g][nt * 16 + col][0]);
      acc[nt] = __builtin_amdgcn_mfma_f32_16x16x32_bf16(a_t, bih, acc[nt], 0, 0, 0);
      bf16x8 bhh = *reinterpret_cast<const bf16x8*>(&whh0L[g][nt * 16 + col][0]);
      acc[nt] = __builtin_amdgcn_mfma_f32_16x16x32_bf16(a_h0, bhh, acc[nt], 0, 0, 0);
    }

    // issue h1 loads now: in flight during layer-0 gate VALU work
    const float4* h1p = reinterpret_cast<const float4*>(h1 + (size_t)(m16 + col) * HH + 8 * g);
    float4 w0 = h1p[0], w1v = h1p[1];

    // ---- layer-0 gates: lane-local in C layout (row=4g+r, k=kk*16+col) ----
#pragma unroll
    for (int kk = 0; kk < 2; ++kk) {
      const int k = kk * 16 + col;
#pragma unroll
      for (int r = 0; r < 4; ++r) {
        const size_t e2 = (size_t)(m16 + mrow + r);
        float iv = fsig(acc[0 + kk][r]);
        float fv = fsig(acc[2 + kk][r]);
        float gv = ftanh(acc[4 + kk][r]);
        float ov = fsig(acc[6 + kk][r]);
        float cn = fv * c0r[kk][r] + iv * gv;
        float hn = ov * ftanh(cn);
        c0out[e2 * HH + k] = cn;
        h0out[e2 * HH + k] = hn;
        hsg[w][k >> 3][mrow + r][k & 7] = f2bf(hn);
      }
    }
    // hsg is PER-WAVE: wave-local LDS fence suffices (no block barrier)
    asm volatile("s_waitcnt lgkmcnt(0)" ::: "memory");

    // ---- layer-1 A fragments ----
    bf16x8 a_hn = *reinterpret_cast<const bf16x8*>(&hsg[w][g][col][0]);
    bf16x8 a_h1;
    a_h1[0] = f2bf(w0.x);  a_h1[1] = f2bf(w0.y);  a_h1[2] = f2bf(w0.z);  a_h1[3] = f2bf(w0.w);
    a_h1[4] = f2bf(w1v.x); a_h1[5] = f2bf(w1v.y); a_h1[6] = f2bf(w1v.z); a_h1[7] = f2bf(w1v.w);

    // c1 loads hide under layer-1 MFMAs
    float c1r[2][4];
#pragma unroll
    for (int kk = 0; kk < 2; ++kk)
#pragma unroll
      for (int r = 0; r < 4; ++r)
        c1r[kk][r] = c1[(size_t)(m16 + mrow + r) * HH + kk * 16 + col];

#pragma unroll
    for (int nt = 0; nt < 8; ++nt) {
      float bv = biasv1[nt];
      f32x4 a = {bv, bv, bv, bv};
      acc[nt] = a;
    }
#pragma unroll
    for (int nt = 0; nt < 8; ++nt) {
      bf16x8 bih = *reinterpret_cast<const bf16x8*>(&wih1L[g][nt * 16 + col][0]);
      acc[nt] = __builtin_amdgcn_mfma_f32_16x16x32_bf16(a_hn, bih, acc[nt], 0, 0, 0);
      bf16x8 bhh = *reinterpret_cast<const bf16x8*>(&whh1L[g][nt * 16 + col][0]);
      acc[nt] = __builtin_amdgcn_mfma_f32_16x16x32_bf16(a_h1, bhh, acc[nt], 0, 0, 0);
    }

    // ---- layer-1 gates + delta partial ----
    float dsum[4] = {0.f, 0.f, 0.f, 0.f};
#pragma unroll
    for (int kk = 0; kk < 2; ++kk) {
      const int k = kk * 16 + col;
      const float wf = kk ? wfc1 : wfc0;
#pragma unroll
      for (int r = 0; r < 4; ++r) {
        const size_t e2 = (size_t)(m16 + mrow + r);
        float iv = fsig(acc[0 + kk][r]);
        float fv = fsig(acc[2 + kk][r]);
        float gv = ftanh(acc[4 + kk][r]);
        float ov = fsig(acc[6 + kk][r]);
        float cn = fv * c1r[kk][r] + iv * gv;
        float hn = ov * ftanh(cn);
        c1out[e2 * HH + k] = cn;
        h1out[e2 * HH + k] = hn;
        dsum[r] += hn * wf;
      }
    }
    // reduce across the 16 lanes of each group (rows 4g..4g+3)
#pragma unroll
    for (int off = 1; off < 16; off <<= 1) {
#pragma unroll
      for (int r = 0; r < 4; ++r) dsum[r] += __shfl_xor(dsum[r], off, 64);
    }
    if (col == 0) {
      const int e4 = m16 + mrow;
      float4 xv = *reinterpret_cast<const float4*>(x + e4);
      float4 dv = {dsum[0] + bfcv, dsum[1] + bfcv, dsum[2] + bfcv, dsum[3] + bfcv};
      *reinterpret_cast<float4*>(dout + e4) = dv;
      float4 xn = {xv.x + dv.x, xv.y + dv.y, xv.z + dv.z, xv.w + dv.w};
      *reinterpret_cast<float4*>(xout + e4) = xn;
    }
  }
  }
}

extern "C" void kernel_launch(void* const* d_in, const int* in_sizes, int n_in,
                              void* d_out, int out_size, void* d_ws, size_t ws_size,
                              hipStream_t stream) {
  const float* x    = (const float*)d_in[0];
  const float* grad = (const float*)d_in[1];
  const float* h0   = (const float*)d_in[2];
  const float* c0   = (const float*)d_in[3];
  const float* h1   = (const float*)d_in[4];
  const float* c1   = (const float*)d_in[5];
  const float* W1   = (const float*)d_in[6];
  const float* b1   = (const float*)d_in[7];
  const float* W2   = (const float*)d_in[8];
  const float* b2   = (const float*)d_in[9];
  const float* Wih0 = (const float*)d_in[10];
  const float* Whh0 = (const float*)d_in[11];
  const float* bih0 = (const float*)d_in[12];
  const float* bhh0 = (const float*)d_in[13];
  const float* Wih1 = (const float*)d_in[14];
  const float* Whh1 = (const float*)d_in[15];
  const float* bih1 = (const float*)d_in[16];
  const float* bhh1 = (const float*)d_in[17];
  const float* Wfc  = (const float*)d_in[18];
  const float* bfc  = (const float*)d_in[19];
  const int BN = in_sizes[0];            // 800000 (divisible by 64, not by 512)
  const int nblk = (BN + BLK - 1) / BLK; // 1563 blocks x (8 waves x 64 elems)
  l2o_fused<<<nblk, BLK, 0, stream>>>(x, grad, h0, c0, h1, c1, W1, b1, W2, b2,
                                      Wih0, Whh0, bih0, bhh0, Wih1, Whh1,
                                      bih1, bhh1, Wfc, bfc, (float*)d_out, BN);
}

// Round 7
// 218.480 us; speedup vs baseline: 1.8650x; 1.8650x over previous
//
#include <hip/hip_runtime.h>

// L2O optimizer fused kernel — R7: R6 geometry (512-thread blocks, 8 waves
// sharing 28KB weight LDS, 3 blocks/CU = 24 waves/CU) with RELAXED register
// bound: __launch_bounds__(512,2). R6's (512,6) forced VGPR=40 -> full spill
// (FETCH/WRITE both ~676MB). R3's code shape needs ~84 VGPR to stay spill-free.
// Layouts:
//  * B-frag LDS [k/8][n][k%8] (bf16): lane l reads 16B at [l>>4][nt*16+(l&15)].
//  * A and B frags use the SAME k-slot mapping -> correctness independent of HW k-order.
//  * C/D layout (HW-verified): col = lane&15, row = (lane>>4)*4 + reg.

typedef __attribute__((ext_vector_type(8))) short bf16x8;
typedef __attribute__((ext_vector_type(4))) float f32x4;

#define HH 32
#define LL 10
#define NG 128
#define NW 8            // waves per block
#define BLK 512         // threads per block

__device__ __forceinline__ short f2bf(float x) {
  __bf16 b = (__bf16)x;                 // HW v_cvt (pairs fuse to v_cvt_pk_bf16_f32)
  return __builtin_bit_cast(short, b);
}
__device__ __forceinline__ float fsig(float x) {
  return __builtin_amdgcn_rcpf(1.0f + __expf(-x));
}
__device__ __forceinline__ float ftanh(float x) {
  return fmaf(2.0f, __builtin_amdgcn_rcpf(1.0f + __expf(-2.0f * x)), -1.0f);
}

__global__ __launch_bounds__(BLK, 2) void l2o_fused(
    const float* __restrict__ x, const float* __restrict__ grad,
    const float* __restrict__ h0, const float* __restrict__ c0,
    const float* __restrict__ h1, const float* __restrict__ c1,
    const float* __restrict__ W1, const float* __restrict__ b1,
    const float* __restrict__ W2, const float* __restrict__ b2,
    const float* __restrict__ Wih0, const float* __restrict__ Whh0,
    const float* __restrict__ bih0, const float* __restrict__ bhh0,
    const float* __restrict__ Wih1, const float* __restrict__ Whh1,
    const float* __restrict__ bih1, const float* __restrict__ bhh1,
    const float* __restrict__ Wfc, const float* __restrict__ bfc,
    float* __restrict__ out, int BNi)
{
  const size_t BN = (size_t)BNi;
  float* __restrict__ xout  = out;
  float* __restrict__ h0out = out + BN;
  float* __restrict__ c0out = out + BN + BN * HH;
  float* __restrict__ h1out = out + BN + 2 * BN * HH;
  float* __restrict__ c1out = out + BN + 3 * BN * HH;
  float* __restrict__ dout  = out + BN + 4 * BN * HH;

  // Weights in B-fragment chunked layout (bf16): 28KB, shared by 8 waves.
  __shared__ __align__(16) short wih0L[2][NG][8];   // K=10 padded to 16
  __shared__ __align__(16) short whh0L[4][NG][8];
  __shared__ __align__(16) short wih1L[4][NG][8];
  __shared__ __align__(16) short whh1L[4][NG][8];
  __shared__ __align__(16) short tsg0[NW][64][8];   // t dims 0..7 (per wave)
  __shared__ __align__(4)  short tsg1[NW][64][2];   // t dims 8..9
  __shared__ __align__(16) short hsg[NW][4][16][8]; // per-wave, per-st h0n staging

  const int tid = threadIdx.x;
  for (int idx = tid; idx < NG * HH; idx += BLK) {  // 4096
    int n = idx >> 5, k = idx & 31;
    whh0L[k >> 3][n][k & 7] = f2bf(Whh0[n * HH + k]);
    wih1L[k >> 3][n][k & 7] = f2bf(Wih1[n * HH + k]);
    whh1L[k >> 3][n][k & 7] = f2bf(Whh1[n * HH + k]);
  }
  for (int idx = tid; idx < NG * 16; idx += BLK) {  // 2048
    int n = idx >> 4, k = idx & 15;
    wih0L[k >> 3][n][k & 7] = (k < LL) ? f2bf(Wih0[n * LL + k]) : (short)0;
  }

  const int lane = tid & 63;
  const int w = tid >> 6;
  const int col = lane & 15;
  const int g = lane >> 4;
  const int mrow = 4 * g;

  float biasv0[8], biasv1[8];
#pragma unroll
  for (int nt = 0; nt < 8; ++nt) {
    biasv0[nt] = bih0[nt * 16 + col] + bhh0[nt * 16 + col];
    biasv1[nt] = bih1[nt * 16 + col] + bhh1[nt * 16 + col];
  }
  const float wfc0 = Wfc[col], wfc1 = Wfc[16 + col];
  const float bfcv = bfc[0];

  const int ebase = blockIdx.x * (NW * 64) + w * 64;  // this wave's 64 elements
  const bool active = ebase < BNi;                     // wave-uniform tail guard

  if (active) { // ---- t-MLP: one element per lane; weights are uniform scalar loads
    float gv = grad[ebase + lane];
    float sg = (gv > 0.f) ? 1.f : ((gv < 0.f) ? -1.f : 0.f);
    float lg = __logf(fabsf(gv) + 1e-14f);
    float u[LL], t[LL];
#pragma unroll
    for (int j = 0; j < LL; ++j)
      u[j] = ftanh(W1[2 * j] * sg + W1[2 * j + 1] * lg + b1[j]);
#pragma unroll
    for (int j = 0; j < LL; ++j) {
      float a = b2[j];
#pragma unroll
      for (int k = 0; k < LL; ++k) a += W2[j * LL + k] * u[k];
      t[j] = a;
    }
    bf16x8 tv0;
#pragma unroll
    for (int s = 0; s < 8; ++s) tv0[s] = f2bf(t[s]);
    *reinterpret_cast<bf16x8*>(&tsg0[w][lane][0]) = tv0;
    tsg1[w][lane][0] = f2bf(t[8]);
    tsg1[w][lane][1] = f2bf(t[9]);
  }
  __syncthreads();   // weights + t staging visible to all (outside the guard)

  if (active) {
#pragma unroll 1
  for (int st = 0; st < 4; ++st) {
    const int m16 = ebase + st * 16;

    // ---- layer-0 A fragments ----
    bf16x8 a_t = {0, 0, 0, 0, 0, 0, 0, 0};        // K=10 padded; g>=2 all zero
    if (g == 0) a_t = *reinterpret_cast<const bf16x8*>(&tsg0[w][st * 16 + col][0]);
    else if (g == 1) {
      a_t[0] = tsg1[w][st * 16 + col][0];
      a_t[1] = tsg1[w][st * 16 + col][1];
    }
    const float4* hp = reinterpret_cast<const float4*>(h0 + (size_t)(m16 + col) * HH + 8 * g);
    float4 v0 = hp[0], v1 = hp[1];
    bf16x8 a_h0;
    a_h0[0] = f2bf(v0.x); a_h0[1] = f2bf(v0.y); a_h0[2] = f2bf(v0.z); a_h0[3] = f2bf(v0.w);
    a_h0[4] = f2bf(v1.x); a_h0[5] = f2bf(v1.y); a_h0[6] = f2bf(v1.z); a_h0[7] = f2bf(v1.w);

    // c0 loads issued here so HBM latency hides under layer-0 MFMAs
    float c0r[2][4];
#pragma unroll
    for (int kk = 0; kk < 2; ++kk)
#pragma unroll
      for (int r = 0; r < 4; ++r)
        c0r[kk][r] = c0[(size_t)(m16 + mrow + r) * HH + kk * 16 + col];

    f32x4 acc[8];
#pragma unroll
    for (int nt = 0; nt < 8; ++nt) {
      float bv = biasv0[nt];
      f32x4 a = {bv, bv, bv, bv};
      acc[nt] = a;
    }
#pragma unroll
    for (int nt = 0; nt < 8; ++nt) {
      bf16x8 bih = {0, 0, 0, 0, 0, 0, 0, 0};
      if (g < 2) bih = *reinterpret_cast<const bf16x8*>(&wih0L[g][nt * 16 + col][0]);
      acc[nt] = __builtin_amdgcn_mfma_f32_16x16x32_bf16(a_t, bih, acc[nt], 0, 0, 0);
      bf16x8 bhh = *reinterpret_cast<const bf16x8*>(&whh0L[g][nt * 16 + col][0]);
      acc[nt] = __builtin_amdgcn_mfma_f32_16x16x32_bf16(a_h0, bhh, acc[nt], 0, 0, 0);
    }

    // issue h1 loads now: in flight during layer-0 gate VALU work
    const float4* h1p = reinterpret_cast<const float4*>(h1 + (size_t)(m16 + col) * HH + 8 * g);
    float4 w0 = h1p[0], w1v = h1p[1];

    // ---- layer-0 gates: lane-local in C layout (row=4g+r, k=kk*16+col) ----
#pragma unroll
    for (int kk = 0; kk < 2; ++kk) {
      const int k = kk * 16 + col;
#pragma unroll
      for (int r = 0; r < 4; ++r) {
        const size_t e2 = (size_t)(m16 + mrow + r);
        float iv = fsig(acc[0 + kk][r]);
        float fv = fsig(acc[2 + kk][r]);
        float gv = ftanh(acc[4 + kk][r]);
        float ov = fsig(acc[6 + kk][r]);
        float cn = fv * c0r[kk][r] + iv * gv;
        float hn = ov * ftanh(cn);
        c0out[e2 * HH + k] = cn;
        h0out[e2 * HH + k] = hn;
        hsg[w][k >> 3][mrow + r][k & 7] = f2bf(hn);
      }
    }
    // hsg is PER-WAVE: wave-local LDS fence suffices (no block barrier)
    asm volatile("s_waitcnt lgkmcnt(0)" ::: "memory");

    // ---- layer-1 A fragments ----
    bf16x8 a_hn = *reinterpret_cast<const bf16x8*>(&hsg[w][g][col][0]);
    bf16x8 a_h1;
    a_h1[0] = f2bf(w0.x);  a_h1[1] = f2bf(w0.y);  a_h1[2] = f2bf(w0.z);  a_h1[3] = f2bf(w0.w);
    a_h1[4] = f2bf(w1v.x); a_h1[5] = f2bf(w1v.y); a_h1[6] = f2bf(w1v.z); a_h1[7] = f2bf(w1v.w);

    // c1 loads hide under layer-1 MFMAs
    float c1r[2][4];
#pragma unroll
    for (int kk = 0; kk < 2; ++kk)
#pragma unroll
      for (int r = 0; r < 4; ++r)
        c1r[kk][r] = c1[(size_t)(m16 + mrow + r) * HH + kk * 16 + col];

#pragma unroll
    for (int nt = 0; nt < 8; ++nt) {
      float bv = biasv1[nt];
      f32x4 a = {bv, bv, bv, bv};
      acc[nt] = a;
    }
#pragma unroll
    for (int nt = 0; nt < 8; ++nt) {
      bf16x8 bih = *reinterpret_cast<const bf16x8*>(&wih1L[g][nt * 16 + col][0]);
      acc[nt] = __builtin_amdgcn_mfma_f32_16x16x32_bf16(a_hn, bih, acc[nt], 0, 0, 0);
      bf16x8 bhh = *reinterpret_cast<const bf16x8*>(&whh1L[g][nt * 16 + col][0]);
      acc[nt] = __builtin_amdgcn_mfma_f32_16x16x32_bf16(a_h1, bhh, acc[nt], 0, 0, 0);
    }

    // ---- layer-1 gates + delta partial ----
    float dsum[4] = {0.f, 0.f, 0.f, 0.f};
#pragma unroll
    for (int kk = 0; kk < 2; ++kk) {
      const int k = kk * 16 + col;
      const float wf = kk ? wfc1 : wfc0;
#pragma unroll
      for (int r = 0; r < 4; ++r) {
        const size_t e2 = (size_t)(m16 + mrow + r);
        float iv = fsig(acc[0 + kk][r]);
        float fv = fsig(acc[2 + kk][r]);
        float gv = ftanh(acc[4 + kk][r]);
        float ov = fsig(acc[6 + kk][r]);
        float cn = fv * c1r[kk][r] + iv * gv;
        float hn = ov * ftanh(cn);
        c1out[e2 * HH + k] = cn;
        h1out[e2 * HH + k] = hn;
        dsum[r] += hn * wf;
      }
    }
    // reduce across the 16 lanes of each group (rows 4g..4g+3)
#pragma unroll
    for (int off = 1; off < 16; off <<= 1) {
#pragma unroll
      for (int r = 0; r < 4; ++r) dsum[r] += __shfl_xor(dsum[r], off, 64);
    }
    if (col == 0) {
      const int e4 = m16 + mrow;
      float4 xv = *reinterpret_cast<const float4*>(x + e4);
      float4 dv = {dsum[0] + bfcv, dsum[1] + bfcv, dsum[2] + bfcv, dsum[3] + bfcv};
      *reinterpret_cast<float4*>(dout + e4) = dv;
      float4 xn = {xv.x + dv.x, xv.y + dv.y, xv.z + dv.z, xv.w + dv.w};
      *reinterpret_cast<float4*>(xout + e4) = xn;
    }
  }
  }
}

extern "C" void kernel_launch(void* const* d_in, const int* in_sizes, int n_in,
                              void* d_out, int out_size, void* d_ws, size_t ws_size,
                              hipStream_t stream) {
  const float* x    = (const float*)d_in[0];
  const float* grad = (const float*)d_in[1];
  const float* h0   = (const float*)d_in[2];
  const float* c0   = (const float*)d_in[3];
  const float* h1   = (const float*)d_in[4];
  const float* c1   = (const float*)d_in[5];
  const float* W1   = (const float*)d_in[6];
  const float* b1   = (const float*)d_in[7];
  const float* W2   = (const float*)d_in[8];
  const float* b2   = (const float*)d_in[9];
  const float* Wih0 = (const float*)d_in[10];
  const float* Whh0 = (const float*)d_in[11];
  const float* bih0 = (const float*)d_in[12];
  const float* bhh0 = (const float*)d_in[13];
  const float* Wih1 = (const float*)d_in[14];
  const float* Whh1 = (const float*)d_in[15];
  const float* bih1 = (const float*)d_in[16];
  const float* bhh1 = (const float*)d_in[17];
  const float* Wfc  = (const float*)d_in[18];
  const float* bfc  = (const float*)d_in[19];
  const int BN = in_sizes[0];            // 800000 (divisible by 64, not by 512)
  const int nblk = (BN + BLK - 1) / BLK; // 1563 blocks x (8 waves x 64 elems)
  l2o_fused<<<nblk, BLK, 0, stream>>>(x, grad, h0, c0, h1, c1, W1, b1, W2, b2,
                                      Wih0, Whh0, bih0, bhh0, Wih1, Whh1,
                                      bih1, bhh1, Wfc, bfc, (float*)d_out, BN);
}

// Round 8
// 209.046 us; speedup vs baseline: 1.9492x; 1.0451x over previous
//
#include <hip/hip_runtime.h>

// L2O optimizer fused kernel — R8: dense-vmem restructure. All global traffic is
// full-line dwordx4 (row-major per-lane); C-layout<->row-major conversion for
// c-inputs and all outputs goes through a per-wave LDS transpose buffer
// [16][36] f32 (stride 144B: rows 16B-aligned; b128 ops at bank floor, b32 ops
// 2-way=free). Cuts per-st vmem 52->18 instrs, eliminates all scattered
// 64B-segment loads/stores (R3/R7's suspected per-CU TA wall: dur invariant to
// occupancy 16->24 waves/CU and to -100us VALU work).
// Layouts:
//  * B-frag LDS [k/8][n][k%8] (bf16): lane l reads 16B at [l>>4][nt*16+(l&15)].
//  * A and B frags use the SAME k-slot mapping -> correctness independent of HW k-order.
//  * C/D layout (HW-verified): col = lane&15, row = (lane>>4)*4 + reg.

typedef __attribute__((ext_vector_type(8))) short bf16x8;
typedef __attribute__((ext_vector_type(4))) float f32x4;

#define HH 32
#define LL 10
#define NG 128
#define NW 8            // waves per block
#define BLK 512         // threads per block
#define TP 36           // transpose-buffer row stride (floats): 144B, 16B-aligned

__device__ __forceinline__ short f2bf(float x) {
  __bf16 b = (__bf16)x;                 // HW v_cvt (pairs fuse to v_cvt_pk_bf16_f32)
  return __builtin_bit_cast(short, b);
}
__device__ __forceinline__ float fsig(float x) {
  return __builtin_amdgcn_rcpf(1.0f + __expf(-x));
}
__device__ __forceinline__ float ftanh(float x) {
  return fmaf(2.0f, __builtin_amdgcn_rcpf(1.0f + __expf(-2.0f * x)), -1.0f);
}
#define LDS_FENCE() asm volatile("s_waitcnt lgkmcnt(0)" ::: "memory")

__global__ __launch_bounds__(BLK, 2) void l2o_fused(
    const float* __restrict__ x, const float* __restrict__ grad,
    const float* __restrict__ h0, const float* __restrict__ c0,
    const float* __restrict__ h1, const float* __restrict__ c1,
    const float* __restrict__ W1, const float* __restrict__ b1,
    const float* __restrict__ W2, const float* __restrict__ b2,
    const float* __restrict__ Wih0, const float* __restrict__ Whh0,
    const float* __restrict__ bih0, const float* __restrict__ bhh0,
    const float* __restrict__ Wih1, const float* __restrict__ Whh1,
    const float* __restrict__ bih1, const float* __restrict__ bhh1,
    const float* __restrict__ Wfc, const float* __restrict__ bfc,
    float* __restrict__ out, int BNi)
{
  const size_t BN = (size_t)BNi;
  float* __restrict__ xout  = out;
  float* __restrict__ h0out = out + BN;
  float* __restrict__ c0out = out + BN + BN * HH;
  float* __restrict__ h1out = out + BN + 2 * BN * HH;
  float* __restrict__ c1out = out + BN + 3 * BN * HH;
  float* __restrict__ dout  = out + BN + 4 * BN * HH;

  // Weights in B-fragment chunked layout (bf16): 28KB, shared by 8 waves.
  __shared__ __align__(16) short wih0L[2][NG][8];   // K=10 padded to 16
  __shared__ __align__(16) short whh0L[4][NG][8];
  __shared__ __align__(16) short wih1L[4][NG][8];
  __shared__ __align__(16) short whh1L[4][NG][8];
  __shared__ __align__(16) short tsg0[NW][64][8];   // t dims 0..7 (per wave)
  __shared__ __align__(4)  short tsg1[NW][64][2];   // t dims 8..9
  __shared__ __align__(16) float tbuf[NW][16][TP];  // per-wave transpose buffer

  const int tid = threadIdx.x;
  for (int idx = tid; idx < NG * HH; idx += BLK) {  // 4096
    int n = idx >> 5, k = idx & 31;
    whh0L[k >> 3][n][k & 7] = f2bf(Whh0[n * HH + k]);
    wih1L[k >> 3][n][k & 7] = f2bf(Wih1[n * HH + k]);
    whh1L[k >> 3][n][k & 7] = f2bf(Whh1[n * HH + k]);
  }
  for (int idx = tid; idx < NG * 16; idx += BLK) {  // 2048
    int n = idx >> 4, k = idx & 15;
    wih0L[k >> 3][n][k & 7] = (k < LL) ? f2bf(Wih0[n * LL + k]) : (short)0;
  }

  const int lane = tid & 63;
  const int w = tid >> 6;
  const int col = lane & 15;
  const int g = lane >> 4;
  const int mrow = 4 * g;

  float biasv0[8], biasv1[8];
#pragma unroll
  for (int nt = 0; nt < 8; ++nt) {
    biasv0[nt] = bih0[nt * 16 + col] + bhh0[nt * 16 + col];
    biasv1[nt] = bih1[nt * 16 + col] + bhh1[nt * 16 + col];
  }
  const float wfc0 = Wfc[col], wfc1 = Wfc[16 + col];
  const float bfcv = bfc[0];

  const int ebase = blockIdx.x * (NW * 64) + w * 64;  // this wave's 64 elements
  const bool active = ebase < BNi;                     // wave-uniform tail guard

  if (active) { // ---- t-MLP: one element per lane; weights are uniform scalar loads
    float gv = grad[ebase + lane];
    float sg = (gv > 0.f) ? 1.f : ((gv < 0.f) ? -1.f : 0.f);
    float lg = __logf(fabsf(gv) + 1e-14f);
    float u[LL], t[LL];
#pragma unroll
    for (int j = 0; j < LL; ++j)
      u[j] = ftanh(W1[2 * j] * sg + W1[2 * j + 1] * lg + b1[j]);
#pragma unroll
    for (int j = 0; j < LL; ++j) {
      float a = b2[j];
#pragma unroll
      for (int k = 0; k < LL; ++k) a += W2[j * LL + k] * u[k];
      t[j] = a;
    }
    bf16x8 tv0;
#pragma unroll
    for (int s = 0; s < 8; ++s) tv0[s] = f2bf(t[s]);
    *reinterpret_cast<bf16x8*>(&tsg0[w][lane][0]) = tv0;
    tsg1[w][lane][0] = f2bf(t[8]);
    tsg1[w][lane][1] = f2bf(t[9]);
  }
  __syncthreads();   // weights + t staging visible to all (outside the guard)

  if (active) {
#pragma unroll 1
  for (int st = 0; st < 4; ++st) {
    const int m16 = ebase + st * 16;
    const size_t rowoff = (size_t)(m16 + col) * HH + 8 * g;  // this lane's row slice

    // ---- ALL global loads up front: 8 dense dwordx4 = 8KB/wave in flight ----
    const float4* h0p = reinterpret_cast<const float4*>(h0 + rowoff);
    float4 hv0 = h0p[0], hv1 = h0p[1];
    const float4* c0p = reinterpret_cast<const float4*>(c0 + rowoff);
    float4 cv0 = c0p[0], cv1 = c0p[1];
    const float4* h1p = reinterpret_cast<const float4*>(h1 + rowoff);
    float4 wv0 = h1p[0], wv1 = h1p[1];
    const float4* c1p = reinterpret_cast<const float4*>(c1 + rowoff);
    float4 dv0 = c1p[0], dv1 = c1p[1];

    // ---- layer-0 A fragments ----
    bf16x8 a_t = {0, 0, 0, 0, 0, 0, 0, 0};        // K=10 padded; g>=2 all zero
    if (g == 0) a_t = *reinterpret_cast<const bf16x8*>(&tsg0[w][st * 16 + col][0]);
    else if (g == 1) {
      a_t[0] = tsg1[w][st * 16 + col][0];
      a_t[1] = tsg1[w][st * 16 + col][1];
    }
    bf16x8 a_h0;
    a_h0[0] = f2bf(hv0.x); a_h0[1] = f2bf(hv0.y); a_h0[2] = f2bf(hv0.z); a_h0[3] = f2bf(hv0.w);
    a_h0[4] = f2bf(hv1.x); a_h0[5] = f2bf(hv1.y); a_h0[6] = f2bf(hv1.z); a_h0[7] = f2bf(hv1.w);

    f32x4 acc[8];
#pragma unroll
    for (int nt = 0; nt < 8; ++nt) {
      float bv = biasv0[nt];
      f32x4 a = {bv, bv, bv, bv};
      acc[nt] = a;
    }
#pragma unroll
    for (int nt = 0; nt < 8; ++nt) {
      bf16x8 bih = {0, 0, 0, 0, 0, 0, 0, 0};
      if (g < 2) bih = *reinterpret_cast<const bf16x8*>(&wih0L[g][nt * 16 + col][0]);
      acc[nt] = __builtin_amdgcn_mfma_f32_16x16x32_bf16(a_t, bih, acc[nt], 0, 0, 0);
      bf16x8 bhh = *reinterpret_cast<const bf16x8*>(&whh0L[g][nt * 16 + col][0]);
      acc[nt] = __builtin_amdgcn_mfma_f32_16x16x32_bf16(a_h0, bhh, acc[nt], 0, 0, 0);
    }

    // ---- use1: c0 rows -> C-layout positions (transpose via tbuf) ----
    *reinterpret_cast<float4*>(&tbuf[w][col][8 * g])     = cv0;
    *reinterpret_cast<float4*>(&tbuf[w][col][8 * g + 4]) = cv1;
    LDS_FENCE();
    float c0r[2][4];
#pragma unroll
    for (int kk = 0; kk < 2; ++kk)
#pragma unroll
      for (int r = 0; r < 4; ++r)
        c0r[kk][r] = tbuf[w][mrow + r][16 * kk + col];
    LDS_FENCE();   // reads done before buffer reuse (WAR)

    // ---- layer-0 gates: lane-local in C layout (row=4g+r, k=kk*16+col) ----
    float hnv[2][4], cnv[2][4];
#pragma unroll
    for (int kk = 0; kk < 2; ++kk)
#pragma unroll
      for (int r = 0; r < 4; ++r) {
        float iv = fsig(acc[0 + kk][r]);
        float fv = fsig(acc[2 + kk][r]);
        float gv = ftanh(acc[4 + kk][r]);
        float ov = fsig(acc[6 + kk][r]);
        float cn = fv * c0r[kk][r] + iv * gv;
        float hn = ov * ftanh(cn);
        cnv[kk][r] = cn;
        hnv[kk][r] = hn;
      }

    // ---- use2: h0n C-pos -> rows; dense store + layer-1 A-frag ----
#pragma unroll
    for (int kk = 0; kk < 2; ++kk)
#pragma unroll
      for (int r = 0; r < 4; ++r)
        tbuf[w][mrow + r][16 * kk + col] = hnv[kk][r];
    LDS_FENCE();
    float4 hnr0 = *reinterpret_cast<const float4*>(&tbuf[w][col][8 * g]);
    float4 hnr1 = *reinterpret_cast<const float4*>(&tbuf[w][col][8 * g + 4]);
    LDS_FENCE();
    *reinterpret_cast<float4*>(h0out + rowoff)     = hnr0;
    *reinterpret_cast<float4*>(h0out + rowoff + 4) = hnr1;
    bf16x8 a_hn;
    a_hn[0] = f2bf(hnr0.x); a_hn[1] = f2bf(hnr0.y); a_hn[2] = f2bf(hnr0.z); a_hn[3] = f2bf(hnr0.w);
    a_hn[4] = f2bf(hnr1.x); a_hn[5] = f2bf(hnr1.y); a_hn[6] = f2bf(hnr1.z); a_hn[7] = f2bf(hnr1.w);

    // ---- use3: c0n C-pos -> rows; dense store ----
#pragma unroll
    for (int kk = 0; kk < 2; ++kk)
#pragma unroll
      for (int r = 0; r < 4; ++r)
        tbuf[w][mrow + r][16 * kk + col] = cnv[kk][r];
    LDS_FENCE();
    float4 cnr0 = *reinterpret_cast<const float4*>(&tbuf[w][col][8 * g]);
    float4 cnr1 = *reinterpret_cast<const float4*>(&tbuf[w][col][8 * g + 4]);
    LDS_FENCE();
    *reinterpret_cast<float4*>(c0out + rowoff)     = cnr0;
    *reinterpret_cast<float4*>(c0out + rowoff + 4) = cnr1;

    // ---- use4: c1 rows -> C-layout positions ----
    *reinterpret_cast<float4*>(&tbuf[w][col][8 * g])     = dv0;
    *reinterpret_cast<float4*>(&tbuf[w][col][8 * g + 4]) = dv1;
    LDS_FENCE();
    float c1r[2][4];
#pragma unroll
    for (int kk = 0; kk < 2; ++kk)
#pragma unroll
      for (int r = 0; r < 4; ++r)
        c1r[kk][r] = tbuf[w][mrow + r][16 * kk + col];
    LDS_FENCE();

    // ---- layer-1 MFMA ----
    bf16x8 a_h1;
    a_h1[0] = f2bf(wv0.x); a_h1[1] = f2bf(wv0.y); a_h1[2] = f2bf(wv0.z); a_h1[3] = f2bf(wv0.w);
    a_h1[4] = f2bf(wv1.x); a_h1[5] = f2bf(wv1.y); a_h1[6] = f2bf(wv1.z); a_h1[7] = f2bf(wv1.w);
#pragma unroll
    for (int nt = 0; nt < 8; ++nt) {
      float bv = biasv1[nt];
      f32x4 a = {bv, bv, bv, bv};
      acc[nt] = a;
    }
#pragma unroll
    for (int nt = 0; nt < 8; ++nt) {
      bf16x8 bih = *reinterpret_cast<const bf16x8*>(&wih1L[g][nt * 16 + col][0]);
      acc[nt] = __builtin_amdgcn_mfma_f32_16x16x32_bf16(a_hn, bih, acc[nt], 0, 0, 0);
      bf16x8 bhh = *reinterpret_cast<const bf16x8*>(&whh1L[g][nt * 16 + col][0]);
      acc[nt] = __builtin_amdgcn_mfma_f32_16x16x32_bf16(a_h1, bhh, acc[nt], 0, 0, 0);
    }

    // ---- layer-1 gates + delta partial ----
    float dsum[4] = {0.f, 0.f, 0.f, 0.f};
#pragma unroll
    for (int kk = 0; kk < 2; ++kk) {
      const float wf = kk ? wfc1 : wfc0;
#pragma unroll
      for (int r = 0; r < 4; ++r) {
        float iv = fsig(acc[0 + kk][r]);
        float fv = fsig(acc[2 + kk][r]);
        float gv = ftanh(acc[4 + kk][r]);
        float ov = fsig(acc[6 + kk][r]);
        float cn = fv * c1r[kk][r] + iv * gv;
        float hn = ov * ftanh(cn);
        cnv[kk][r] = cn;
        hnv[kk][r] = hn;
        dsum[r] += hn * wf;
      }
    }

    // ---- use5: h1n C-pos -> rows; dense store ----
#pragma unroll
    for (int kk = 0; kk < 2; ++kk)
#pragma unroll
      for (int r = 0; r < 4; ++r)
        tbuf[w][mrow + r][16 * kk + col] = hnv[kk][r];
    LDS_FENCE();
    float4 h1r0 = *reinterpret_cast<const float4*>(&tbuf[w][col][8 * g]);
    float4 h1r1 = *reinterpret_cast<const float4*>(&tbuf[w][col][8 * g + 4]);
    LDS_FENCE();
    *reinterpret_cast<float4*>(h1out + rowoff)     = h1r0;
    *reinterpret_cast<float4*>(h1out + rowoff + 4) = h1r1;

    // ---- use6: c1n C-pos -> rows; dense store ----
#pragma unroll
    for (int kk = 0; kk < 2; ++kk)
#pragma unroll
      for (int r = 0; r < 4; ++r)
        tbuf[w][mrow + r][16 * kk + col] = cnv[kk][r];
    LDS_FENCE();
    float4 c1r0 = *reinterpret_cast<const float4*>(&tbuf[w][col][8 * g]);
    float4 c1r1 = *reinterpret_cast<const float4*>(&tbuf[w][col][8 * g + 4]);
    LDS_FENCE();
    *reinterpret_cast<float4*>(c1out + rowoff)     = c1r0;
    *reinterpret_cast<float4*>(c1out + rowoff + 4) = c1r1;

    // ---- delta: reduce across the 16 lanes of each group (rows 4g..4g+3) ----
#pragma unroll
    for (int off = 1; off < 16; off <<= 1) {
#pragma unroll
      for (int r = 0; r < 4; ++r) dsum[r] += __shfl_xor(dsum[r], off, 64);
    }
    if (col == 0) {
      const int e4 = m16 + mrow;
      float4 xv = *reinterpret_cast<const float4*>(x + e4);
      float4 dv = {dsum[0] + bfcv, dsum[1] + bfcv, dsum[2] + bfcv, dsum[3] + bfcv};
      *reinterpret_cast<float4*>(dout + e4) = dv;
      float4 xn = {xv.x + dv.x, xv.y + dv.y, xv.z + dv.z, xv.w + dv.w};
      *reinterpret_cast<float4*>(xout + e4) = xn;
    }
  }
  }
}

extern "C" void kernel_launch(void* const* d_in, const int* in_sizes, int n_in,
                              void* d_out, int out_size, void* d_ws, size_t ws_size,
                              hipStream_t stream) {
  const float* x    = (const float*)d_in[0];
  const float* grad = (const float*)d_in[1];
  const float* h0   = (const float*)d_in[2];
  const float* c0   = (const float*)d_in[3];
  const float* h1   = (const float*)d_in[4];
  const float* c1   = (const float*)d_in[5];
  const float* W1   = (const float*)d_in[6];
  const float* b1   = (const float*)d_in[7];
  const float* W2   = (const float*)d_in[8];
  const float* b2   = (const float*)d_in[9];
  const float* Wih0 = (const float*)d_in[10];
  const float* Whh0 = (const float*)d_in[11];
  const float* bih0 = (const float*)d_in[12];
  const float* bhh0 = (const float*)d_in[13];
  const float* Wih1 = (const float*)d_in[14];
  const float* Whh1 = (const float*)d_in[15];
  const float* bih1 = (const float*)d_in[16];
  const float* bhh1 = (const float*)d_in[17];
  const float* Wfc  = (const float*)d_in[18];
  const float* bfc  = (const float*)d_in[19];
  const int BN = in_sizes[0];            // 800000 (divisible by 64, not by 512)
  const int nblk = (BN + BLK - 1) / BLK; // 1563 blocks x (8 waves x 64 elems)
  l2o_fused<<<nblk, BLK, 0, stream>>>(x, grad, h0, c0, h1, c1, W1, b1, W2, b2,
                                      Wih0, Whh0, bih0, bhh0, Wih1, Whh1,
                                      bih1, bhh1, Wfc, bfc, (float*)d_out, BN);
}

// Round 9
// 208.788 us; speedup vs baseline: 1.9516x; 1.0012x over previous
//
#include <hip/hip_runtime.h>

// L2O optimizer fused kernel — R9: R8 dense-vmem structure + 2-deep tile
// pipeline (T14) implemented SROA-PROOF: prefetched tile lives in individually
// NAMED float4 locals via token-pasting macros (no arrays/structs/lambdas ->
// cannot be demoted to scratch; R4/R5 failed exactly there). Tile st+1's 8
// global dwordx4 issue at the top of tile st's body, keeping HBM queues fed
// through the ~3K-cycle compute body (duty-cycle/convoy theory of the ~4TB/s
// plateau). Tile-0 loads also overlap the t-MLP prologue.
// Layouts:
//  * B-frag LDS [k/8][n][k%8] (bf16): lane l reads 16B at [l>>4][nt*16+(l&15)].
//  * A and B frags use the SAME k-slot mapping -> correctness independent of HW k-order.
//  * C/D layout (HW-verified): col = lane&15, row = (lane>>4)*4 + reg.

typedef __attribute__((ext_vector_type(8))) short bf16x8;
typedef __attribute__((ext_vector_type(4))) float f32x4;

#define HH 32
#define LL 10
#define NG 128
#define NW 8            // waves per block
#define BLK 512         // threads per block
#define TP 36           // transpose-buffer row stride (floats): 144B, 16B-aligned

__device__ __forceinline__ short f2bf(float x) {
  __bf16 b = (__bf16)x;                 // HW v_cvt (pairs fuse to v_cvt_pk_bf16_f32)
  return __builtin_bit_cast(short, b);
}
__device__ __forceinline__ float fsig(float x) {
  return __builtin_amdgcn_rcpf(1.0f + __expf(-x));
}
__device__ __forceinline__ float ftanh(float x) {
  return fmaf(2.0f, __builtin_amdgcn_rcpf(1.0f + __expf(-2.0f * x)), -1.0f);
}
#define LDS_FENCE() asm volatile("s_waitcnt lgkmcnt(0)" ::: "memory")

// ---- tile load into NAMED scalars (P = A or B) ----
#define LOADT(P, STV) do {                                                   \
    const size_t ro_ = (size_t)(ebase + (STV) * 16 + col) * HH + 8 * g;      \
    P##hv0 = reinterpret_cast<const float4*>(h0 + ro_)[0];                   \
    P##hv1 = reinterpret_cast<const float4*>(h0 + ro_)[1];                   \
    P##cv0 = reinterpret_cast<const float4*>(c0 + ro_)[0];                   \
    P##cv1 = reinterpret_cast<const float4*>(c0 + ro_)[1];                   \
    P##wv0 = reinterpret_cast<const float4*>(h1 + ro_)[0];                   \
    P##wv1 = reinterpret_cast<const float4*>(h1 + ro_)[1];                   \
    P##dv0 = reinterpret_cast<const float4*>(c1 + ro_)[0];                   \
    P##dv1 = reinterpret_cast<const float4*>(c1 + ro_)[1];                   \
  } while (0)

// ---- full st body consuming tile P ----
#define COMPUTE(P, STV) do {                                                  \
    const int m16_ = ebase + (STV) * 16;                                      \
    const size_t rowoff_ = (size_t)(m16_ + col) * HH + 8 * g;                 \
    bf16x8 a_t = {0, 0, 0, 0, 0, 0, 0, 0};                                    \
    if (g == 0) a_t = *reinterpret_cast<const bf16x8*>(&tsg0[w][(STV) * 16 + col][0]); \
    else if (g == 1) {                                                        \
      a_t[0] = tsg1[w][(STV) * 16 + col][0];                                  \
      a_t[1] = tsg1[w][(STV) * 16 + col][1];                                  \
    }                                                                         \
    bf16x8 a_h0;                                                              \
    a_h0[0] = f2bf(P##hv0.x); a_h0[1] = f2bf(P##hv0.y);                       \
    a_h0[2] = f2bf(P##hv0.z); a_h0[3] = f2bf(P##hv0.w);                       \
    a_h0[4] = f2bf(P##hv1.x); a_h0[5] = f2bf(P##hv1.y);                       \
    a_h0[6] = f2bf(P##hv1.z); a_h0[7] = f2bf(P##hv1.w);                       \
    f32x4 acc[8];                                                             \
    _Pragma("unroll")                                                         \
    for (int nt = 0; nt < 8; ++nt) {                                          \
      float bv = biasv0[nt];                                                  \
      f32x4 a = {bv, bv, bv, bv};                                             \
      acc[nt] = a;                                                            \
    }                                                                         \
    _Pragma("unroll")                                                         \
    for (int nt = 0; nt < 8; ++nt) {                                          \
      bf16x8 bih = {0, 0, 0, 0, 0, 0, 0, 0};                                  \
      if (g < 2) bih = *reinterpret_cast<const bf16x8*>(&wih0L[g][nt * 16 + col][0]); \
      acc[nt] = __builtin_amdgcn_mfma_f32_16x16x32_bf16(a_t, bih, acc[nt], 0, 0, 0);  \
      bf16x8 bhh = *reinterpret_cast<const bf16x8*>(&whh0L[g][nt * 16 + col][0]);     \
      acc[nt] = __builtin_amdgcn_mfma_f32_16x16x32_bf16(a_h0, bhh, acc[nt], 0, 0, 0); \
    }                                                                         \
    *reinterpret_cast<float4*>(&tbuf[w][col][8 * g])     = P##cv0;            \
    *reinterpret_cast<float4*>(&tbuf[w][col][8 * g + 4]) = P##cv1;            \
    LDS_FENCE();                                                              \
    float c0r[2][4];                                                          \
    _Pragma("unroll")                                                         \
    for (int kk = 0; kk < 2; ++kk)                                            \
      _Pragma("unroll")                                                       \
      for (int r = 0; r < 4; ++r)                                             \
        c0r[kk][r] = tbuf[w][mrow + r][16 * kk + col];                        \
    LDS_FENCE();                                                              \
    float hnv[2][4], cnv[2][4];                                               \
    _Pragma("unroll")                                                         \
    for (int kk = 0; kk < 2; ++kk)                                            \
      _Pragma("unroll")                                                       \
      for (int r = 0; r < 4; ++r) {                                           \
        float iv = fsig(acc[0 + kk][r]);                                      \
        float fv = fsig(acc[2 + kk][r]);                                      \
        float gv = ftanh(acc[4 + kk][r]);                                     \
        float ov = fsig(acc[6 + kk][r]);                                      \
        float cn = fv * c0r[kk][r] + iv * gv;                                 \
        float hn = ov * ftanh(cn);                                            \
        cnv[kk][r] = cn;                                                      \
        hnv[kk][r] = hn;                                                      \
      }                                                                       \
    _Pragma("unroll")                                                         \
    for (int kk = 0; kk < 2; ++kk)                                            \
      _Pragma("unroll")                                                       \
      for (int r = 0; r < 4; ++r)                                             \
        tbuf[w][mrow + r][16 * kk + col] = hnv[kk][r];                        \
    LDS_FENCE();                                                              \
    float4 hnr0 = *reinterpret_cast<const float4*>(&tbuf[w][col][8 * g]);     \
    float4 hnr1 = *reinterpret_cast<const float4*>(&tbuf[w][col][8 * g + 4]); \
    LDS_FENCE();                                                              \
    *reinterpret_cast<float4*>(h0out + rowoff_)     = hnr0;                   \
    *reinterpret_cast<float4*>(h0out + rowoff_ + 4) = hnr1;                   \
    bf16x8 a_hn;                                                              \
    a_hn[0] = f2bf(hnr0.x); a_hn[1] = f2bf(hnr0.y);                           \
    a_hn[2] = f2bf(hnr0.z); a_hn[3] = f2bf(hnr0.w);                           \
    a_hn[4] = f2bf(hnr1.x); a_hn[5] = f2bf(hnr1.y);                           \
    a_hn[6] = f2bf(hnr1.z); a_hn[7] = f2bf(hnr1.w);                           \
    _Pragma("unroll")                                                         \
    for (int kk = 0; kk < 2; ++kk)                                            \
      _Pragma("unroll")                                                       \
      for (int r = 0; r < 4; ++r)                                             \
        tbuf[w][mrow + r][16 * kk + col] = cnv[kk][r];                        \
    LDS_FENCE();                                                              \
    float4 cnr0 = *reinterpret_cast<const float4*>(&tbuf[w][col][8 * g]);     \
    float4 cnr1 = *reinterpret_cast<const float4*>(&tbuf[w][col][8 * g + 4]); \
    LDS_FENCE();                                                              \
    *reinterpret_cast<float4*>(c0out + rowoff_)     = cnr0;                   \
    *reinterpret_cast<float4*>(c0out + rowoff_ + 4) = cnr1;                   \
    *reinterpret_cast<float4*>(&tbuf[w][col][8 * g])     = P##dv0;            \
    *reinterpret_cast<float4*>(&tbuf[w][col][8 * g + 4]) = P##dv1;            \
    LDS_FENCE();                                                              \
    float c1r[2][4];                                                          \
    _Pragma("unroll")                                                         \
    for (int kk = 0; kk < 2; ++kk)                                            \
      _Pragma("unroll")                                                       \
      for (int r = 0; r < 4; ++r)                                             \
        c1r[kk][r] = tbuf[w][mrow + r][16 * kk + col];                        \
    LDS_FENCE();                                                              \
    bf16x8 a_h1;                                                              \
    a_h1[0] = f2bf(P##wv0.x); a_h1[1] = f2bf(P##wv0.y);                       \
    a_h1[2] = f2bf(P##wv0.z); a_h1[3] = f2bf(P##wv0.w);                       \
    a_h1[4] = f2bf(P##wv1.x); a_h1[5] = f2bf(P##wv1.y);                       \
    a_h1[6] = f2bf(P##wv1.z); a_h1[7] = f2bf(P##wv1.w);                       \
    _Pragma("unroll")                                                         \
    for (int nt = 0; nt < 8; ++nt) {                                          \
      float bv = biasv1[nt];                                                  \
      f32x4 a = {bv, bv, bv, bv};                                             \
      acc[nt] = a;                                                            \
    }                                                                         \
    _Pragma("unroll")                                                         \
    for (int nt = 0; nt < 8; ++nt) {                                          \
      bf16x8 bih = *reinterpret_cast<const bf16x8*>(&wih1L[g][nt * 16 + col][0]);     \
      acc[nt] = __builtin_amdgcn_mfma_f32_16x16x32_bf16(a_hn, bih, acc[nt], 0, 0, 0); \
      bf16x8 bhh = *reinterpret_cast<const bf16x8*>(&whh1L[g][nt * 16 + col][0]);     \
      acc[nt] = __builtin_amdgcn_mfma_f32_16x16x32_bf16(a_h1, bhh, acc[nt], 0, 0, 0); \
    }                                                                         \
    float dsum[4] = {0.f, 0.f, 0.f, 0.f};                                     \
    _Pragma("unroll")                                                         \
    for (int kk = 0; kk < 2; ++kk) {                                          \
      const float wf = kk ? wfc1 : wfc0;                                      \
      _Pragma("unroll")                                                       \
      for (int r = 0; r < 4; ++r) {                                           \
        float iv = fsig(acc[0 + kk][r]);                                      \
        float fv = fsig(acc[2 + kk][r]);                                      \
        float gv = ftanh(acc[4 + kk][r]);                                     \
        float ov = fsig(acc[6 + kk][r]);                                      \
        float cn = fv * c1r[kk][r] + iv * gv;                                 \
        float hn = ov * ftanh(cn);                                            \
        cnv[kk][r] = cn;                                                      \
        hnv[kk][r] = hn;                                                      \
        dsum[r] += hn * wf;                                                   \
      }                                                                       \
    }                                                                         \
    _Pragma("unroll")                                                         \
    for (int kk = 0; kk < 2; ++kk)                                            \
      _Pragma("unroll")                                                       \
      for (int r = 0; r < 4; ++r)                                             \
        tbuf[w][mrow + r][16 * kk + col] = hnv[kk][r];                        \
    LDS_FENCE();                                                              \
    float4 h1r0 = *reinterpret_cast<const float4*>(&tbuf[w][col][8 * g]);     \
    float4 h1r1 = *reinterpret_cast<const float4*>(&tbuf[w][col][8 * g + 4]); \
    LDS_FENCE();                                                              \
    *reinterpret_cast<float4*>(h1out + rowoff_)     = h1r0;                   \
    *reinterpret_cast<float4*>(h1out + rowoff_ + 4) = h1r1;                   \
    _Pragma("unroll")                                                         \
    for (int kk = 0; kk < 2; ++kk)                                            \
      _Pragma("unroll")                                                       \
      for (int r = 0; r < 4; ++r)                                             \
        tbuf[w][mrow + r][16 * kk + col] = cnv[kk][r];                        \
    LDS_FENCE();                                                              \
    float4 c1r0 = *reinterpret_cast<const float4*>(&tbuf[w][col][8 * g]);     \
    float4 c1r1 = *reinterpret_cast<const float4*>(&tbuf[w][col][8 * g + 4]); \
    LDS_FENCE();                                                              \
    *reinterpret_cast<float4*>(c1out + rowoff_)     = c1r0;                   \
    *reinterpret_cast<float4*>(c1out + rowoff_ + 4) = c1r1;                   \
    _Pragma("unroll")                                                         \
    for (int off = 1; off < 16; off <<= 1) {                                  \
      _Pragma("unroll")                                                       \
      for (int r = 0; r < 4; ++r) dsum[r] += __shfl_xor(dsum[r], off, 64);    \
    }                                                                         \
    if (col == 0) {                                                           \
      const int e4 = m16_ + mrow;                                             \
      float4 xv = *reinterpret_cast<const float4*>(x + e4);                   \
      float4 dv = {dsum[0] + bfcv, dsum[1] + bfcv, dsum[2] + bfcv, dsum[3] + bfcv}; \
      *reinterpret_cast<float4*>(dout + e4) = dv;                             \
      float4 xn = {xv.x + dv.x, xv.y + dv.y, xv.z + dv.z, xv.w + dv.w};       \
      *reinterpret_cast<float4*>(xout + e4) = xn;                             \
    }                                                                         \
  } while (0)

__global__ __launch_bounds__(BLK, 2) void l2o_fused(
    const float* __restrict__ x, const float* __restrict__ grad,
    const float* __restrict__ h0, const float* __restrict__ c0,
    const float* __restrict__ h1, const float* __restrict__ c1,
    const float* __restrict__ W1, const float* __restrict__ b1,
    const float* __restrict__ W2, const float* __restrict__ b2,
    const float* __restrict__ Wih0, const float* __restrict__ Whh0,
    const float* __restrict__ bih0, const float* __restrict__ bhh0,
    const float* __restrict__ Wih1, const float* __restrict__ Whh1,
    const float* __restrict__ bih1, const float* __restrict__ bhh1,
    const float* __restrict__ Wfc, const float* __restrict__ bfc,
    float* __restrict__ out, int BNi)
{
  const size_t BN = (size_t)BNi;
  float* __restrict__ xout  = out;
  float* __restrict__ h0out = out + BN;
  float* __restrict__ c0out = out + BN + BN * HH;
  float* __restrict__ h1out = out + BN + 2 * BN * HH;
  float* __restrict__ c1out = out + BN + 3 * BN * HH;
  float* __restrict__ dout  = out + BN + 4 * BN * HH;

  // Weights in B-fragment chunked layout (bf16): 28KB, shared by 8 waves.
  __shared__ __align__(16) short wih0L[2][NG][8];   // K=10 padded to 16
  __shared__ __align__(16) short whh0L[4][NG][8];
  __shared__ __align__(16) short wih1L[4][NG][8];
  __shared__ __align__(16) short whh1L[4][NG][8];
  __shared__ __align__(16) short tsg0[NW][64][8];   // t dims 0..7 (per wave)
  __shared__ __align__(4)  short tsg1[NW][64][2];   // t dims 8..9
  __shared__ __align__(16) float tbuf[NW][16][TP];  // per-wave transpose buffer

  const int tid = threadIdx.x;
  const int lane = tid & 63;
  const int w = tid >> 6;
  const int col = lane & 15;
  const int g = lane >> 4;
  const int mrow = 4 * g;

  const int ebase = blockIdx.x * (NW * 64) + w * 64;  // this wave's 64 elements
  const bool active = ebase < BNi;                     // wave-uniform tail guard

  // ---- pipeline tile state: NAMED scalars only (SSA; cannot hit scratch) ----
  float4 Ahv0, Ahv1, Acv0, Acv1, Awv0, Awv1, Adv0, Adv1;
  float4 Bhv0, Bhv1, Bcv0, Bcv1, Bwv0, Bwv1, Bdv0, Bdv1;

  // tile-0 loads FIRST: in flight across weight staging + t-MLP + barrier
  if (active) LOADT(A, 0);

  for (int idx = tid; idx < NG * HH; idx += BLK) {  // 4096
    int n = idx >> 5, k = idx & 31;
    whh0L[k >> 3][n][k & 7] = f2bf(Whh0[n * HH + k]);
    wih1L[k >> 3][n][k & 7] = f2bf(Wih1[n * HH + k]);
    whh1L[k >> 3][n][k & 7] = f2bf(Whh1[n * HH + k]);
  }
  for (int idx = tid; idx < NG * 16; idx += BLK) {  // 2048
    int n = idx >> 4, k = idx & 15;
    wih0L[k >> 3][n][k & 7] = (k < LL) ? f2bf(Wih0[n * LL + k]) : (short)0;
  }

  float biasv0[8], biasv1[8];
#pragma unroll
  for (int nt = 0; nt < 8; ++nt) {
    biasv0[nt] = bih0[nt * 16 + col] + bhh0[nt * 16 + col];
    biasv1[nt] = bih1[nt * 16 + col] + bhh1[nt * 16 + col];
  }
  const float wfc0 = Wfc[col], wfc1 = Wfc[16 + col];
  const float bfcv = bfc[0];

  if (active) { // ---- t-MLP: one element per lane; weights are uniform scalar loads
    float gv = grad[ebase + lane];
    float sg = (gv > 0.f) ? 1.f : ((gv < 0.f) ? -1.f : 0.f);
    float lg = __logf(fabsf(gv) + 1e-14f);
    float u[LL], t[LL];
#pragma unroll
    for (int j = 0; j < LL; ++j)
      u[j] = ftanh(W1[2 * j] * sg + W1[2 * j + 1] * lg + b1[j]);
#pragma unroll
    for (int j = 0; j < LL; ++j) {
      float a = b2[j];
#pragma unroll
      for (int k = 0; k < LL; ++k) a += W2[j * LL + k] * u[k];
      t[j] = a;
    }
    bf16x8 tv0;
#pragma unroll
    for (int s = 0; s < 8; ++s) tv0[s] = f2bf(t[s]);
    *reinterpret_cast<bf16x8*>(&tsg0[w][lane][0]) = tv0;
    tsg1[w][lane][0] = f2bf(t[8]);
    tsg1[w][lane][1] = f2bf(t[9]);
  }
  __syncthreads();   // weights + t staging visible to all (outside the guard)

  if (active) {
    LOADT(B, 1);        // prefetch tile 1; in flight through tile 0's body
    COMPUTE(A, 0);
    LOADT(A, 2);        // prefetch tile 2
    COMPUTE(B, 1);
    LOADT(B, 3);        // prefetch tile 3
    COMPUTE(A, 2);
    COMPUTE(B, 3);
  }
}

extern "C" void kernel_launch(void* const* d_in, const int* in_sizes, int n_in,
                              void* d_out, int out_size, void* d_ws, size_t ws_size,
                              hipStream_t stream) {
  const float* x    = (const float*)d_in[0];
  const float* grad = (const float*)d_in[1];
  const float* h0   = (const float*)d_in[2];
  const float* c0   = (const float*)d_in[3];
  const float* h1   = (const float*)d_in[4];
  const float* c1   = (const float*)d_in[5];
  const float* W1   = (const float*)d_in[6];
  const float* b1   = (const float*)d_in[7];
  const float* W2   = (const float*)d_in[8];
  const float* b2   = (const float*)d_in[9];
  const float* Wih0 = (const float*)d_in[10];
  const float* Whh0 = (const float*)d_in[11];
  const float* bih0 = (const float*)d_in[12];
  const float* bhh0 = (const float*)d_in[13];
  const float* Wih1 = (const float*)d_in[14];
  const float* Whh1 = (const float*)d_in[15];
  const float* bih1 = (const float*)d_in[16];
  const float* bhh1 = (const float*)d_in[17];
  const float* Wfc  = (const float*)d_in[18];
  const float* bfc  = (const float*)d_in[19];
  const int BN = in_sizes[0];            // 800000 (divisible by 64, not by 512)
  const int nblk = (BN + BLK - 1) / BLK; // 1563 blocks x (8 waves x 64 elems)
  l2o_fused<<<nblk, BLK, 0, stream>>>(x, grad, h0, c0, h1, c1, W1, b1, W2, b2,
                                      Wih0, Whh0, bih0, bhh0, Wih1, Whh1,
                                      bih1, bhh1, Wfc, bfc, (float*)d_out, BN);
}

// Round 10
// 208.392 us; speedup vs baseline: 1.9553x; 1.0019x over previous
//
#include <hip/hip_runtime.h>

// L2O optimizer fused kernel — R10: SWAPPED-OPERAND MFMA formulation.
// D = mfma(A=weights, B=states): D col = element, row = gate-dim. Each lane
// then holds gates of ONE element (e=lane&15) at k in {4g+r, 16+4g+r} — so
// c0/c1 inputs and all h/c outputs are aligned dwordx4 row-segments with NO
// transpose. Only h0n needs a k-regroup (one bf16 LDS round trip, 2 fences/tile
// vs R8's 12). Layer-0 bias folded into the K=10->16 pad column (w[:,10]=bias,
// t[10]=1). Weight staging & A-frag reads identical to previous rounds
// (sigma_A == sigma_B slot symmetry proven by R1 correctness).
// C/D layout (HW-verified): col = lane&15, row = (lane>>4)*4 + reg.

typedef __attribute__((ext_vector_type(8))) short bf16x8;
typedef __attribute__((ext_vector_type(4))) short bf16x4;
typedef __attribute__((ext_vector_type(4))) float f32x4;

#define HH 32
#define LL 10
#define NG 128
#define NW 8            // waves per block
#define BLK 512         // threads per block
#define TPS 36          // tbuf row stride in shorts (72B; keeps 16B alignment)

__device__ __forceinline__ short f2bf(float x) {
  __bf16 b = (__bf16)x;
  return __builtin_bit_cast(short, b);
}
__device__ __forceinline__ float fsig(float x) {
  return __builtin_amdgcn_rcpf(1.0f + __expf(-x));
}
__device__ __forceinline__ float ftanh(float x) {
  return fmaf(2.0f, __builtin_amdgcn_rcpf(1.0f + __expf(-2.0f * x)), -1.0f);
}
#define LDS_FENCE() asm volatile("s_waitcnt lgkmcnt(0)" ::: "memory")

// 2-deep prefetch of the h-streams (consumed first, by the MFMAs)
#define LOADH(P, STV) do {                                                    \
    const size_t ro_ = (size_t)(ebase + (STV) * 16 + col) * HH + 8 * g;       \
    P##hv0 = reinterpret_cast<const float4*>(h0 + ro_)[0];                    \
    P##hv1 = reinterpret_cast<const float4*>(h0 + ro_)[1];                    \
    P##wv0 = reinterpret_cast<const float4*>(h1 + ro_)[0];                    \
    P##wv1 = reinterpret_cast<const float4*>(h1 + ro_)[1];                    \
  } while (0)

#define COMPUTE(P, STV) do {                                                  \
    const int m16_ = ebase + (STV) * 16;                                      \
    const size_t ro_ = (size_t)(m16_ + col) * HH;                             \
    /* c-streams: aligned row-segment loads (k=4g..4g+3 and 16+4g..16+4g+3) */\
    float4 cv0 = *reinterpret_cast<const float4*>(c0 + ro_ + 4 * g);          \
    float4 cv1 = *reinterpret_cast<const float4*>(c0 + ro_ + 16 + 4 * g);     \
    float4 dv0 = *reinterpret_cast<const float4*>(c1 + ro_ + 4 * g);          \
    float4 dv1 = *reinterpret_cast<const float4*>(c1 + ro_ + 16 + 4 * g);     \
    /* B operands (states) */                                                 \
    bf16x8 b_t = {0, 0, 0, 0, 0, 0, 0, 0};                                    \
    if (g < 2) b_t = *reinterpret_cast<const bf16x8*>(&tsg[w][(STV) * 16 + col][8 * g]); \
    bf16x8 b_h0;                                                              \
    b_h0[0] = f2bf(P##hv0.x); b_h0[1] = f2bf(P##hv0.y);                       \
    b_h0[2] = f2bf(P##hv0.z); b_h0[3] = f2bf(P##hv0.w);                       \
    b_h0[4] = f2bf(P##hv1.x); b_h0[5] = f2bf(P##hv1.y);                       \
    b_h0[6] = f2bf(P##hv1.z); b_h0[7] = f2bf(P##hv1.w);                       \
    f32x4 acc[8];                                                             \
    _Pragma("unroll")                                                         \
    for (int nt = 0; nt < 8; ++nt) { f32x4 z = {0.f, 0.f, 0.f, 0.f}; acc[nt] = z; } \
    _Pragma("unroll")                                                         \
    for (int nt = 0; nt < 8; ++nt) {                                          \
      bf16x8 a_ih = *reinterpret_cast<const bf16x8*>(&wih0L[g & 1][nt * 16 + col][0]); \
      acc[nt] = __builtin_amdgcn_mfma_f32_16x16x32_bf16(a_ih, b_t, acc[nt], 0, 0, 0);  \
      bf16x8 a_hh = *reinterpret_cast<const bf16x8*>(&whh0L[g][nt * 16 + col][0]);     \
      acc[nt] = __builtin_amdgcn_mfma_f32_16x16x32_bf16(a_hh, b_h0, acc[nt], 0, 0, 0); \
    }                                                                         \
    /* layer-0 gates: lane-local, element e=col, k=16kk+4g+r */               \
    float hnv[2][4], cnv[2][4];                                               \
    _Pragma("unroll")                                                         \
    for (int kk = 0; kk < 2; ++kk)                                            \
      _Pragma("unroll")                                                       \
      for (int r = 0; r < 4; ++r) {                                           \
        float iv = fsig(acc[kk][r]);                                          \
        float fv = fsig(acc[2 + kk][r]);                                      \
        float gv = ftanh(acc[4 + kk][r]);                                     \
        float ov = fsig(acc[6 + kk][r]);                                      \
        float cp = kk ? cv1[r] : cv0[r];                                      \
        float cn = fv * cp + iv * gv;                                         \
        cnv[kk][r] = cn;                                                      \
        hnv[kk][r] = ov * ftanh(cn);                                          \
      }                                                                       \
    { /* direct aligned stores, no transpose */                               \
      float4 s0 = {cnv[0][0], cnv[0][1], cnv[0][2], cnv[0][3]};               \
      float4 s1 = {cnv[1][0], cnv[1][1], cnv[1][2], cnv[1][3]};               \
      *reinterpret_cast<float4*>(c0out + ro_ + 4 * g)      = s0;              \
      *reinterpret_cast<float4*>(c0out + ro_ + 16 + 4 * g) = s1;              \
      float4 t0 = {hnv[0][0], hnv[0][1], hnv[0][2], hnv[0][3]};               \
      float4 t1 = {hnv[1][0], hnv[1][1], hnv[1][2], hnv[1][3]};               \
      *reinterpret_cast<float4*>(h0out + ro_ + 4 * g)      = t0;              \
      *reinterpret_cast<float4*>(h0out + ro_ + 16 + 4 * g) = t1;              \
    }                                                                         \
    /* h0n k-regroup via bf16 tbuf: write own k-positions, read k=8g..8g+7 */ \
    {                                                                         \
      bf16x4 p0 = {f2bf(hnv[0][0]), f2bf(hnv[0][1]), f2bf(hnv[0][2]), f2bf(hnv[0][3])}; \
      bf16x4 p1 = {f2bf(hnv[1][0]), f2bf(hnv[1][1]), f2bf(hnv[1][2]), f2bf(hnv[1][3])}; \
      *reinterpret_cast<bf16x4*>(&tbuf[w][col][4 * g])      = p0;             \
      *reinterpret_cast<bf16x4*>(&tbuf[w][col][16 + 4 * g]) = p1;             \
    }                                                                         \
    LDS_FENCE();                                                              \
    bf16x8 b_hn = *reinterpret_cast<const bf16x8*>(&tbuf[w][col][8 * g]);     \
    LDS_FENCE();   /* WAR: reads complete before next tile's writes */        \
    bf16x8 b_h1;                                                              \
    b_h1[0] = f2bf(P##wv0.x); b_h1[1] = f2bf(P##wv0.y);                       \
    b_h1[2] = f2bf(P##wv0.z); b_h1[3] = f2bf(P##wv0.w);                       \
    b_h1[4] = f2bf(P##wv1.x); b_h1[5] = f2bf(P##wv1.y);                       \
    b_h1[6] = f2bf(P##wv1.z); b_h1[7] = f2bf(P##wv1.w);                       \
    _Pragma("unroll")                                                         \
    for (int nt = 0; nt < 8; ++nt) acc[nt] = biasv1[nt];                      \
    _Pragma("unroll")                                                         \
    for (int nt = 0; nt < 8; ++nt) {                                          \
      bf16x8 a_ih = *reinterpret_cast<const bf16x8*>(&wih1L[g][nt * 16 + col][0]);     \
      acc[nt] = __builtin_amdgcn_mfma_f32_16x16x32_bf16(a_ih, b_hn, acc[nt], 0, 0, 0); \
      bf16x8 a_hh = *reinterpret_cast<const bf16x8*>(&whh1L[g][nt * 16 + col][0]);     \
      acc[nt] = __builtin_amdgcn_mfma_f32_16x16x32_bf16(a_hh, b_h1, acc[nt], 0, 0, 0); \
    }                                                                         \
    _Pragma("unroll")                                                         \
    for (int kk = 0; kk < 2; ++kk)                                            \
      _Pragma("unroll")                                                       \
      for (int r = 0; r < 4; ++r) {                                           \
        float iv = fsig(acc[kk][r]);                                          \
        float fv = fsig(acc[2 + kk][r]);                                      \
        float gv = ftanh(acc[4 + kk][r]);                                     \
        float ov = fsig(acc[6 + kk][r]);                                      \
        float cp = kk ? dv1[r] : dv0[r];                                      \
        float cn = fv * cp + iv * gv;                                         \
        cnv[kk][r] = cn;                                                      \
        hnv[kk][r] = ov * ftanh(cn);                                          \
      }                                                                       \
    {                                                                         \
      float4 s0 = {cnv[0][0], cnv[0][1], cnv[0][2], cnv[0][3]};               \
      float4 s1 = {cnv[1][0], cnv[1][1], cnv[1][2], cnv[1][3]};               \
      *reinterpret_cast<float4*>(c1out + ro_ + 4 * g)      = s0;              \
      *reinterpret_cast<float4*>(c1out + ro_ + 16 + 4 * g) = s1;              \
      float4 t0 = {hnv[0][0], hnv[0][1], hnv[0][2], hnv[0][3]};               \
      float4 t1 = {hnv[1][0], hnv[1][1], hnv[1][2], hnv[1][3]};               \
      *reinterpret_cast<float4*>(h1out + ro_ + 4 * g)      = t0;              \
      *reinterpret_cast<float4*>(h1out + ro_ + 16 + 4 * g) = t1;              \
    }                                                                         \
    float dsum = 0.f;                                                         \
    _Pragma("unroll")                                                         \
    for (int r = 0; r < 4; ++r)                                               \
      dsum += hnv[0][r] * wfcA[r] + hnv[1][r] * wfcB[r];                      \
    dsum += __shfl_xor(dsum, 16, 64);                                         \
    dsum += __shfl_xor(dsum, 32, 64);                                         \
    if (g == 0) {                                                             \
      float xv = x[m16_ + col];                                               \
      float dv = dsum + bfcv;                                                 \
      dout[m16_ + col] = dv;                                                  \
      xout[m16_ + col] = xv + dv;                                             \
    }                                                                         \
  } while (0)

__global__ __launch_bounds__(BLK, 2) void l2o_fused(
    const float* __restrict__ x, const float* __restrict__ grad,
    const float* __restrict__ h0, const float* __restrict__ c0,
    const float* __restrict__ h1, const float* __restrict__ c1,
    const float* __restrict__ W1, const float* __restrict__ b1,
    const float* __restrict__ W2, const float* __restrict__ b2,
    const float* __restrict__ Wih0, const float* __restrict__ Whh0,
    const float* __restrict__ bih0, const float* __restrict__ bhh0,
    const float* __restrict__ Wih1, const float* __restrict__ Whh1,
    const float* __restrict__ bih1, const float* __restrict__ bhh1,
    const float* __restrict__ Wfc, const float* __restrict__ bfc,
    float* __restrict__ out, int BNi)
{
  const size_t BN = (size_t)BNi;
  float* __restrict__ xout  = out;
  float* __restrict__ h0out = out + BN;
  float* __restrict__ c0out = out + BN + BN * HH;
  float* __restrict__ h1out = out + BN + 2 * BN * HH;
  float* __restrict__ c1out = out + BN + 3 * BN * HH;
  float* __restrict__ dout  = out + BN + 4 * BN * HH;

  // Weights as A-fragments (same chunked layout/reads as all prior rounds).
  __shared__ __align__(16) short wih0L[2][NG][8];   // K=16: k<10 weights, k=10 bias col, rest 0
  __shared__ __align__(16) short whh0L[4][NG][8];
  __shared__ __align__(16) short wih1L[4][NG][8];
  __shared__ __align__(16) short whh1L[4][NG][8];
  __shared__ __align__(16) short tsg[NW][64][16];   // t (k=0..9), 1.0 at k=10, 0 pad
  __shared__ __align__(16) short tbuf[NW][16][TPS]; // per-wave bf16 h0n regroup buffer

  const int tid = threadIdx.x;
  const int lane = tid & 63;
  const int w = tid >> 6;
  const int col = lane & 15;
  const int g = lane >> 4;

  const int ebase = blockIdx.x * (NW * 64) + w * 64;
  const bool active = ebase < BNi;                   // wave-uniform tail guard

  // prefetch state: named scalars only
  float4 Ahv0, Ahv1, Awv0, Awv1;
  float4 Bhv0, Bhv1, Bwv0, Bwv1;
  if (active) LOADH(A, 0);   // in flight across staging + t-MLP + barrier

  for (int idx = tid; idx < NG * HH; idx += BLK) {  // 4096
    int n = idx >> 5, k = idx & 31;
    whh0L[k >> 3][n][k & 7] = f2bf(Whh0[n * HH + k]);
    wih1L[k >> 3][n][k & 7] = f2bf(Wih1[n * HH + k]);
    whh1L[k >> 3][n][k & 7] = f2bf(Whh1[n * HH + k]);
  }
  for (int idx = tid; idx < NG * 16; idx += BLK) {  // 2048
    int n = idx >> 4, k = idx & 15;
    short v;
    if (k < LL)       v = f2bf(Wih0[n * LL + k]);
    else if (k == LL) v = f2bf(bih0[n] + bhh0[n]);  // bias column (t[10]=1)
    else              v = 0;
    wih0L[k >> 3][n][k & 7] = v;
  }

  // layer-1 bias in C-layout: biasv1[nt][r] = b(16nt+4g+r), aligned float4 loads
  f32x4 biasv1[8];
#pragma unroll
  for (int nt = 0; nt < 8; ++nt) {
    float4 a = *reinterpret_cast<const float4*>(bih1 + nt * 16 + 4 * g);
    float4 b = *reinterpret_cast<const float4*>(bhh1 + nt * 16 + 4 * g);
    f32x4 s = {a.x + b.x, a.y + b.y, a.z + b.z, a.w + b.w};
    biasv1[nt] = s;
  }
  float4 wfcA = *reinterpret_cast<const float4*>(Wfc + 4 * g);
  float4 wfcB = *reinterpret_cast<const float4*>(Wfc + 16 + 4 * g);
  const float bfcv = bfc[0];

  if (active) { // ---- t-MLP: one element per lane ----
    float gv = grad[ebase + lane];
    float sg = (gv > 0.f) ? 1.f : ((gv < 0.f) ? -1.f : 0.f);
    float lg = __logf(fabsf(gv) + 1e-14f);
    float u[LL], t[LL];
#pragma unroll
    for (int j = 0; j < LL; ++j)
      u[j] = ftanh(W1[2 * j] * sg + W1[2 * j + 1] * lg + b1[j]);
#pragma unroll
    for (int j = 0; j < LL; ++j) {
      float a = b2[j];
#pragma unroll
      for (int k = 0; k < LL; ++k) a += W2[j * LL + k] * u[k];
      t[j] = a;
    }
    bf16x8 tv0, tv1;
#pragma unroll
    for (int s = 0; s < 8; ++s) tv0[s] = f2bf(t[s]);
    tv1[0] = f2bf(t[8]); tv1[1] = f2bf(t[9]);
    tv1[2] = 0x3F80;                      // bf16 1.0 — bias column multiplier
#pragma unroll
    for (int s = 3; s < 8; ++s) tv1[s] = 0;
    *reinterpret_cast<bf16x8*>(&tsg[w][lane][0]) = tv0;
    *reinterpret_cast<bf16x8*>(&tsg[w][lane][8]) = tv1;
  }
  __syncthreads();

  if (active) {
    LOADH(B, 1);
    COMPUTE(A, 0);
    LOADH(A, 2);
    COMPUTE(B, 1);
    LOADH(B, 3);
    COMPUTE(A, 2);
    COMPUTE(B, 3);
  }
}

extern "C" void kernel_launch(void* const* d_in, const int* in_sizes, int n_in,
                              void* d_out, int out_size, void* d_ws, size_t ws_size,
                              hipStream_t stream) {
  const float* x    = (const float*)d_in[0];
  const float* grad = (const float*)d_in[1];
  const float* h0   = (const float*)d_in[2];
  const float* c0   = (const float*)d_in[3];
  const float* h1   = (const float*)d_in[4];
  const float* c1   = (const float*)d_in[5];
  const float* W1   = (const float*)d_in[6];
  const float* b1   = (const float*)d_in[7];
  const float* W2   = (const float*)d_in[8];
  const float* b2   = (const float*)d_in[9];
  const float* Wih0 = (const float*)d_in[10];
  const float* Whh0 = (const float*)d_in[11];
  const float* bih0 = (const float*)d_in[12];
  const float* bhh0 = (const float*)d_in[13];
  const float* Wih1 = (const float*)d_in[14];
  const float* Whh1 = (const float*)d_in[15];
  const float* bih1 = (const float*)d_in[16];
  const float* bhh1 = (const float*)d_in[17];
  const float* Wfc  = (const float*)d_in[18];
  const float* bfc  = (const float*)d_in[19];
  const int BN = in_sizes[0];            // 800000
  const int nblk = (BN + BLK - 1) / BLK; // 1563 blocks x (8 waves x 64 elems)
  l2o_fused<<<nblk, BLK, 0, stream>>>(x, grad, h0, c0, h1, c1, W1, b1, W2, b2,
                                      Wih0, Whh0, bih0, bhh0, Wih1, Whh1,
                                      bih1, bhh1, Wfc, bfc, (float*)d_out, BN);
}